// Round 10
// baseline (12819.131 us; speedup 1.0000x reference)
//
#include <hip/hip_runtime.h>
#include <math.h>

typedef unsigned short u16;
typedef __attribute__((ext_vector_type(8))) short bf16x8;   // 8 bf16 in 4 VGPRs
typedef __attribute__((ext_vector_type(4))) float f32x4;

#define TENC 20
#define TDEC 25
#define MTB 64          // samples per block
#define HSTR 136        // h LDS row stride (u16): 272B, b128-aligned
#define XSTRD 40        // x LDS row stride (u16): 80B, b128-aligned
#define CSTR 129        // c LDS row stride (f32)

// ---- weight fragment layout in ws (u16 offsets) ----
// Per matrix: [kt][t(4)][w(8)][lane(64)][16: hi8|lo8]   (32768 u16 per kt)
// Element (kt,t,w,l,hi/lo j) = split( W_orig[n][k] ), n = t*128 + w*16 + (l&15),
// k = kt*32 + (l>>4)*8 + j  (zero-padded if k >= K).
// Matrix bases padded +512 u16 to break power-of-2 L2 set aliasing.
#define W_E0IH 0        // K=7   nkt=1  sz 32768
#define W_E0HH 33280    // K=128 nkt=4  sz 131072
#define W_E1IH 164864   // K=128 nkt=4
#define W_E1HH 296448   // K=128 nkt=4
#define W_D0IH 428032   // K=2   nkt=1  sz 32768
#define W_D0HH 461312   // K=128 nkt=4
#define W_D1IH 592896   // K=128 nkt=4
#define W_D1HH 724480   // K=128 nkt=4
#define W_TOTAL 855552
#define BIAS_BYTE_OFF (W_TOTAL*2)   // then 4 x 512 floats: e0,e1,d0,d1 fragments

__device__ __forceinline__ void split16(float v, u16& hi, u16& lo) {
  unsigned int u = __float_as_uint(v);
  hi = (u16)(u >> 16);                              // truncated bf16 hi
  float hif = __uint_as_float(u & 0xffff0000u);
  lo = (u16)(__float_as_uint(v - hif) >> 16);       // bf16(lo), residual ~2^-16 rel
}

__global__ void prep_kernel(
    const float* __restrict__ e0ih, const float* __restrict__ e0hh,
    const float* __restrict__ e1ih, const float* __restrict__ e1hh,
    const float* __restrict__ d0ih, const float* __restrict__ d0hh,
    const float* __restrict__ d1ih, const float* __restrict__ d1hh,
    const float* __restrict__ be0i, const float* __restrict__ be0h,
    const float* __restrict__ be1i, const float* __restrict__ be1h,
    const float* __restrict__ bd0i, const float* __restrict__ bd0h,
    const float* __restrict__ bd1i, const float* __restrict__ bd1h,
    u16* __restrict__ wsw, float* __restrict__ wsb)
{
  int idx = blockIdx.x * blockDim.x + threadIdx.x;
  if (idx < W_TOTAL) {
    const float* src; int K, nkt, off;
    if (idx < W_E0HH)      { src=e0ih; K=7;   nkt=1; off=W_E0IH; }
    else if (idx < W_E1IH) { src=e0hh; K=128; nkt=4; off=W_E0HH; }
    else if (idx < W_E1HH) { src=e1ih; K=128; nkt=4; off=W_E1IH; }
    else if (idx < W_D0IH) { src=e1hh; K=128; nkt=4; off=W_E1HH; }
    else if (idx < W_D0HH) { src=d0ih; K=2;   nkt=1; off=W_D0IH; }
    else if (idx < W_D1IH) { src=d0hh; K=128; nkt=4; off=W_D0HH; }
    else if (idx < W_D1HH) { src=d1ih; K=128; nkt=4; off=W_D1IH; }
    else                   { src=d1hh; K=128; nkt=4; off=W_D1HH; }
    int n = idx - off;
    if (n >= nkt*32768) { wsw[idx] = 0; return; }   // base-pad region
    int kt = n >> 15;
    int r  = n & 32767;
    int t   = r >> 13;
    int w   = (r >> 10) & 7;
    int l   = (r >> 4) & 63;
    int j16 = r & 15;
    int pass = j16 >> 3, j = j16 & 7;
    int k  = kt*32 + (l >> 4)*8 + j;
    int ng = t*128 + w*16 + (l & 15);
    float v = (k < K) ? src[ng*K + k] : 0.0f;
    u16 hi, lo; split16(v, hi, lo);
    wsw[idx] = (pass == 0) ? hi : lo;
  } else if (idx < W_TOTAL + 2048) {
    int b = idx - W_TOTAL;
    int set = b >> 9, r = b & 511;
    int t = r & 3, hl = (r >> 2) & 15, w = r >> 6;
    int n = t*128 + w*16 + hl;
    float v;
    if      (set == 0) v = be0i[n] + be0h[n];
    else if (set == 1) v = be1i[n] + be1h[n];
    else if (set == 2) v = bd0i[n] + bd0h[n];
    else               v = bd1i[n] + bd1h[n];
    wsb[b] = v;
  }
}

__device__ __forceinline__ float sigm(float x) { return 1.0f / (1.0f + __expf(-x)); }
__device__ __forceinline__ float tanh_f(float x) {
  float e = __expf(2.0f * x);          // inf/0 saturate gracefully to +/-1
  return 1.0f - 2.0f / (e + 1.0f);
}

// acc[m(4)][t(4)] 16x16 tiles; A from LDS hi/lo bf16 arrays (row = sample, k-contig);
// B fragments streamed from prepped global (hi/lo interleaved 32B).
// 3-term split: AhBh + AhBl + AlBh.
template<int NKT>
__device__ __forceinline__ void gemm_frag(f32x4 acc[4][4],
    const u16* Ahi, const u16* Alo, const int astride,
    const u16* __restrict__ Wf, int w, int l)
{
  const int g = l >> 4, hl = l & 15;
  #pragma unroll
  for (int kt = 0; kt < NKT; ++kt) {
    const int kb = kt*32 + g*8;
    bf16x8 ah[4], al[4];
    #pragma unroll
    for (int m = 0; m < 4; ++m) {
      ah[m] = *(const bf16x8*)(Ahi + (m*16 + hl)*astride + kb);
      al[m] = *(const bf16x8*)(Alo + (m*16 + hl)*astride + kb);
    }
    #pragma unroll
    for (int t = 0; t < 4; ++t) {
      const u16* wp = Wf + (((kt*4 + t)*8 + w)*64 + l)*16;
      bf16x8 bh = *(const bf16x8*)(wp);
      bf16x8 bl = *(const bf16x8*)(wp + 8);
      #pragma unroll
      for (int m = 0; m < 4; ++m) {
        acc[m][t] = __builtin_amdgcn_mfma_f32_16x16x32_bf16(ah[m], bh, acc[m][t], 0, 0, 0);
        acc[m][t] = __builtin_amdgcn_mfma_f32_16x16x32_bf16(ah[m], bl, acc[m][t], 0, 0, 0);
        acc[m][t] = __builtin_amdgcn_mfma_f32_16x16x32_bf16(al[m], bh, acc[m][t], 0, 0, 0);
      }
    }
  }
}

// One LSTM layer step for the block's 64-sample tile.
// acc tile t = gate t (i,f,g,o) for hiddens w*16+(l&15); C/D rows = samples.
// Cell state lives in LDS (cbuf), each (row,col) owned by exactly one thread.
template<int NKT_IH>
__device__ __forceinline__ void layer_step(
    const u16* xhi, const u16* xlo, int xstride,
    u16* hhi, u16* hlo, float* cbuf,
    const u16* __restrict__ Wih, const u16* __restrict__ Whh,
    const float* __restrict__ biasf,
    int w, int l)
{
  const int g = l >> 4, hl = l & 15;
  const int col = w*16 + hl;
  f32x4 acc[4][4];
  float4 bb = *(const float4*)(biasf + col*4);
  const float bv[4] = {bb.x, bb.y, bb.z, bb.w};
  #pragma unroll
  for (int m = 0; m < 4; ++m)
    #pragma unroll
    for (int t = 0; t < 4; ++t) {
      f32x4 a; a[0] = bv[t]; a[1] = bv[t]; a[2] = bv[t]; a[3] = bv[t];
      acc[m][t] = a;
    }
  gemm_frag<NKT_IH>(acc, xhi, xlo, xstride, Wih, w, l);
  gemm_frag<4>(acc, hhi, hlo, HSTR, Whh, w, l);

  __syncthreads();   // all gemm reads of h done before overwrite
  #pragma unroll
  for (int m = 0; m < 4; ++m)
    #pragma unroll
    for (int r = 0; r < 4; ++r) {
      int row = m*16 + g*4 + r;            // C/D: row = (l>>4)*4 + reg
      float iv = sigm(acc[m][0][r]);
      float fv = sigm(acc[m][1][r]);
      float gv = tanh_f(acc[m][2][r]);
      float ov = sigm(acc[m][3][r]);
      float c  = fv * cbuf[row*CSTR + col] + iv * gv;
      cbuf[row*CSTR + col] = c;
      float h  = ov * tanh_f(c);
      u16 a_, b_; split16(h, a_, b_);
      hhi[row*HSTR + col] = a_;
      hlo[row*HSTR + col] = b_;
    }
  __syncthreads();
}

__global__ __launch_bounds__(512) void lstm_main(
    const float* __restrict__ target,
    const u16* __restrict__ wsw, const float* __restrict__ wsb,
    const float* __restrict__ outW, const float* __restrict__ outB,
    float* __restrict__ out)
{
  __shared__ u16 h0hi[MTB*HSTR], h0lo[MTB*HSTR];
  __shared__ u16 h1hi[MTB*HSTR], h1lo[MTB*HSTR];
  __shared__ u16 xhi[MTB*XSTRD], xlo[MTB*XSTRD];
  __shared__ float cs0[MTB*CSTR], cs1[MTB*CSTR];   // cell states, f32
  __shared__ float ps[8*MTB];

  const int tid = threadIdx.x;
  const int w = tid >> 6, l = tid & 63;
  const long sbase = (long)blockIdx.x * MTB;

  for (int i = tid; i < MTB*HSTR; i += 512) { h0hi[i]=0; h0lo[i]=0; h1hi[i]=0; h1lo[i]=0; }
  for (int i = tid; i < MTB*XSTRD; i += 512) { xhi[i]=0; xlo[i]=0; }
  for (int i = tid; i < MTB*CSTR; i += 512) { cs0[i]=0.f; cs1[i]=0.f; }
  __syncthreads();

  // ---------------- encoder ----------------
  for (int t = 0; t < TENC; ++t) {
    if (tid < 7*MTB) {
      int s = tid / 7, d = tid - s*7;
      float v = target[(sbase + s)*(TENC*7) + t*7 + d];
      u16 a_, b_; split16(v, a_, b_);
      xhi[s*XSTRD + d] = a_;
      xlo[s*XSTRD + d] = b_;
    }
    __syncthreads();
    layer_step<1>(xhi, xlo, XSTRD, h0hi, h0lo, cs0, wsw + W_E0IH, wsw + W_E0HH, wsb + 0,    w, l);
    layer_step<4>(h0hi, h0lo, HSTR, h1hi, h1lo, cs1, wsw + W_E1IH, wsw + W_E1HH, wsb + 512, w, l);
  }

  // ---------------- decoder ----------------
  for (int i = tid; i < MTB*XSTRD; i += 512) { xhi[i]=0; xlo[i]=0; }  // x0 = zeros(B,2)
  __syncthreads();
  const float ob0 = outB[0], ob1 = outB[1];

  for (int p = 0; p < TDEC; ++p) {
    layer_step<1>(xhi, xlo, XSTRD, h0hi, h0lo, cs0, wsw + W_D0IH, wsw + W_D0HH, wsb + 1024, w, l);
    layer_step<4>(h0hi, h0lo, HSTR, h1hi, h1lo, cs1, wsw + W_D1IH, wsw + W_D1HH, wsb + 1536, w, l);

    // projection: pred[s][o] = h1[s,:] . outW[o,:] + outB[o]
    {
      int s = tid & (MTB-1), oq = tid >> 6;     // oq = q*2 + o
      int o = oq & 1, q = oq >> 1;
      const float* wo = outW + o*128 + q*32;
      const u16* phh = h1hi + s*HSTR + q*32;
      const u16* phl = h1lo + s*HSTR + q*32;
      float a = 0.f;
      #pragma unroll 8
      for (int k = 0; k < 32; ++k) {
        float hv = __uint_as_float(((unsigned int)phh[k]) << 16)
                 + __uint_as_float(((unsigned int)phl[k]) << 16);
        a = fmaf(hv, wo[k], a);
      }
      ps[oq*MTB + s] = a;
    }
    __syncthreads();
    if (tid < 2*MTB) {
      int s = tid & (MTB-1), o = tid >> 6;
      float pred = ps[(0+o)*MTB+s] + ps[(2+o)*MTB+s] + ps[(4+o)*MTB+s] + ps[(6+o)*MTB+s]
                 + (o ? ob1 : ob0);
      out[((sbase + s)*TDEC + p)*2 + o] = pred;
      u16 a_, b_; split16(pred, a_, b_);
      xhi[s*XSTRD + o] = a_;
      xlo[s*XSTRD + o] = b_;
    }
    __syncthreads();
  }
}

extern "C" void kernel_launch(void* const* d_in, const int* in_sizes, int n_in,
                              void* d_out, int out_size, void* d_ws, size_t ws_size,
                              hipStream_t stream)
{
  const float* target = (const float*)d_in[0];
  const float* e0ih=(const float*)d_in[4],  *e0hh=(const float*)d_in[5];
  const float* be0i=(const float*)d_in[6],  *be0h=(const float*)d_in[7];
  const float* e1ih=(const float*)d_in[8],  *e1hh=(const float*)d_in[9];
  const float* be1i=(const float*)d_in[10], *be1h=(const float*)d_in[11];
  const float* d0ih=(const float*)d_in[12], *d0hh=(const float*)d_in[13];
  const float* bd0i=(const float*)d_in[14], *bd0h=(const float*)d_in[15];
  const float* d1ih=(const float*)d_in[16], *d1hh=(const float*)d_in[17];
  const float* bd1i=(const float*)d_in[18], *bd1h=(const float*)d_in[19];
  const float* outW=(const float*)d_in[20], *outB=(const float*)d_in[21];
  u16*   wsw = (u16*)d_ws;
  float* wsb = (float*)((char*)d_ws + BIAS_BYTE_OFF);
  float* out = (float*)d_out;
  const int B = in_sizes[0] / (TENC*7);     // 65536

  hipLaunchKernelGGL(prep_kernel, dim3((W_TOTAL + 2048 + 255)/256), dim3(256), 0, stream,
      e0ih,e0hh,e1ih,e1hh,d0ih,d0hh,d1ih,d1hh,
      be0i,be0h,be1i,be1h,bd0i,bd0h,bd1i,bd1h, wsw, wsb);
  hipLaunchKernelGGL(lstm_main, dim3(B/MTB), dim3(512), 0, stream,
      target, wsw, wsb, outW, outB, out);
}